// Round 2
// baseline (749.705 us; speedup 1.0000x reference)
//
#include <hip/hip_runtime.h>
#include <hip/hip_bf16.h>

#define B_ 128
#define L_ 2048
#define D_ 256
#define H_ 512
#define U_ 256

// ---------------------------------------------------------------------------
// Kernel A: ph[b][u] = b1[u] + b2[u] + sum_k hidden[b][k] * W2[k][u]
// (both biases folded; they are additive inside the tanh argument)
// ---------------------------------------------------------------------------
__global__ __launch_bounds__(256) void ka_proj_h(
    const float* __restrict__ hidden, const float* __restrict__ W2,
    const float* __restrict__ b1, const float* __restrict__ b2,
    float* __restrict__ ph) {
  int b = blockIdx.x;
  int u = threadIdx.x;
  __shared__ float hs[H_];
  for (int k = u; k < H_; k += 256) hs[k] = hidden[b * H_ + k];
  __syncthreads();
  float acc = b1[u] + b2[u];
#pragma unroll 8
  for (int k = 0; k < H_; ++k) acc += hs[k] * W2[k * U_ + u];
  ph[b * U_ + u] = acc;
}

// ---------------------------------------------------------------------------
// Kernel B: logits[b][l] = sum_u tanh( features[b,l,:]·W1[:,u] + ph[b,u] ) * V[u]
// Tile: 128 rows x 256 cols per block (256 threads).
// Thread tile: 8 rows (stride 16) x 16 cols (tc*4 + q*64 + i).
// ---------------------------------------------------------------------------
#define TL 128
#define KC 32
#define FPAD 36  // 144B row stride: 16B-aligned, tr-groups on distinct banks

__global__ __launch_bounds__(256, 2) void kb_logits(
    const float* __restrict__ features, const float* __restrict__ W1,
    const float* __restrict__ ph, const float* __restrict__ V,
    float* __restrict__ logits) {
  __shared__ float wT[KC][U_];   // 32 KB
  __shared__ float fT[TL][FPAD]; // 18 KB

  const int tid = threadIdx.x;
  const int tc = tid & 15;
  const int tr = tid >> 4;
  const int bidx = blockIdx.x;
  const int b = bidx >> 4;            // L_/TL = 16 tiles per batch
  const int l0 = (bidx & 15) * TL;
  const float* fbase = features + ((size_t)b * L_ + l0) * D_;

  float acc[8][16];
#pragma unroll
  for (int r = 0; r < 8; ++r)
#pragma unroll
    for (int c = 0; c < 16; ++c) acc[r][c] = 0.f;

  for (int kc = 0; kc < D_; kc += KC) {
    // stage W1 chunk [KC][256]: 2048 float4, 8 per thread, coalesced
#pragma unroll
    for (int i = 0; i < 8; ++i) {
      int idx = tid + i * 256;
      int k = idx >> 6;
      int u4 = idx & 63;
      *(float4*)&wT[k][u4 * 4] =
          *(const float4*)&W1[(size_t)(kc + k) * U_ + u4 * 4];
    }
    // stage features chunk [TL][KC]: 1024 float4, 4 per thread
#pragma unroll
    for (int i = 0; i < 4; ++i) {
      int idx = tid + i * 256;
      int row = idx >> 3;
      int k4 = idx & 7;
      *(float4*)&fT[row][k4 * 4] =
          *(const float4*)&fbase[(size_t)row * D_ + kc + k4 * 4];
    }
    __syncthreads();

#pragma unroll
    for (int kk = 0; kk < KC; kk += 4) {
      float4 fv[8];
#pragma unroll
      for (int r = 0; r < 8; ++r)
        fv[r] = *(const float4*)&fT[tr + 16 * r][kk];
#pragma unroll
      for (int j = 0; j < 4; ++j) {
        float4 wv[4];
#pragma unroll
        for (int q = 0; q < 4; ++q)
          wv[q] = *(const float4*)&wT[kk + j][tc * 4 + q * 64];
#pragma unroll
        for (int r = 0; r < 8; ++r) {
          float f = ((const float*)&fv[r])[j];
#pragma unroll
          for (int q = 0; q < 4; ++q) {
            acc[r][q * 4 + 0] += f * wv[q].x;
            acc[r][q * 4 + 1] += f * wv[q].y;
            acc[r][q * 4 + 2] += f * wv[q].z;
            acc[r][q * 4 + 3] += f * wv[q].w;
          }
        }
      }
    }
    __syncthreads();
  }

  // epilogue: tanh + dot with V, reduce across the 16 tc lanes per row
  float phv[16], vv[16];
#pragma unroll
  for (int q = 0; q < 4; ++q) {
    *(float4*)&phv[q * 4] = *(const float4*)&ph[b * U_ + tc * 4 + q * 64];
    *(float4*)&vv[q * 4] = *(const float4*)&V[tc * 4 + q * 64];
  }
#pragma unroll
  for (int r = 0; r < 8; ++r) {
    float part = 0.f;
#pragma unroll
    for (int c = 0; c < 16; ++c) {
      float x = acc[r][c] + phv[c];
      float e = __expf(2.f * x);
      float s = 1.f - 2.f * __builtin_amdgcn_rcpf(e + 1.f);  // tanh(x), inf/0-safe
      part += s * vv[c];
    }
    part += __shfl_xor(part, 1, 16);
    part += __shfl_xor(part, 2, 16);
    part += __shfl_xor(part, 4, 16);
    part += __shfl_xor(part, 8, 16);
    if (tc == 0) logits[b * L_ + l0 + tr + 16 * r] = part;
  }
}

// ---------------------------------------------------------------------------
// Kernel C: softmax over L per batch row; writes attention weights to d_out
// ---------------------------------------------------------------------------
__global__ __launch_bounds__(256) void kc_softmax(
    const float* __restrict__ logits, float* __restrict__ wout) {
  int b = blockIdx.x;
  int tid = threadIdx.x;
  const float* lrow = logits + b * L_;
  float v[8];
  *(float4*)&v[0] = *(const float4*)&lrow[tid * 8];
  *(float4*)&v[4] = *(const float4*)&lrow[tid * 8 + 4];

  float m = v[0];
#pragma unroll
  for (int i = 1; i < 8; ++i) m = fmaxf(m, v[i]);
#pragma unroll
  for (int off = 1; off <= 32; off <<= 1) m = fmaxf(m, __shfl_xor(m, off, 64));
  __shared__ float sm[4];
  if ((tid & 63) == 0) sm[tid >> 6] = m;
  __syncthreads();
  m = fmaxf(fmaxf(sm[0], sm[1]), fmaxf(sm[2], sm[3]));

  float s = 0.f;
#pragma unroll
  for (int i = 0; i < 8; ++i) {
    v[i] = __expf(v[i] - m);
    s += v[i];
  }
#pragma unroll
  for (int off = 1; off <= 32; off <<= 1) s += __shfl_xor(s, off, 64);
  __shared__ float ss[4];
  if ((tid & 63) == 0) ss[tid >> 6] = s;
  __syncthreads();
  s = ss[0] + ss[1] + ss[2] + ss[3];

  float inv = 1.f / s;
#pragma unroll
  for (int i = 0; i < 8; ++i) v[i] *= inv;
  *(float4*)&wout[b * L_ + tid * 8] = *(float4*)&v[0];
  *(float4*)&wout[b * L_ + tid * 8 + 4] = *(float4*)&v[4];
}

// ---------------------------------------------------------------------------
// Kernel D: partial context: partials[b][chunk][d] = sum_{l in chunk} w*f
// block = (b, chunk of 256 l); 4 wave-groups of 64 l each; float4 over d
// ---------------------------------------------------------------------------
__global__ __launch_bounds__(256) void kd_partial(
    const float* __restrict__ features, const float* __restrict__ w,
    float* __restrict__ partials) {
  int bidx = blockIdx.x;  // B * 8
  int b = bidx >> 3;
  int chunk = bidx & 7;
  int tid = threadIdx.x;
  int lq = tid >> 6;  // wave id
  int dq = tid & 63;
  int l0 = chunk * 256 + lq * 64;
  const float* fb = features + ((size_t)b * L_ + l0) * D_ + dq * 4;
  const float* wb = w + b * L_ + l0;
  float4 acc = {0.f, 0.f, 0.f, 0.f};
#pragma unroll 4
  for (int i = 0; i < 64; ++i) {
    float wt = wb[i];  // wave-uniform -> scalar load
    float4 fv = *(const float4*)(fb + (size_t)i * D_);
    acc.x += wt * fv.x;
    acc.y += wt * fv.y;
    acc.z += wt * fv.z;
    acc.w += wt * fv.w;
  }
  __shared__ float red[4][256];
  *(float4*)&red[lq][dq * 4] = acc;
  __syncthreads();
  int d = tid;
  float ssum = red[0][d] + red[1][d] + red[2][d] + red[3][d];
  partials[(size_t)(b * 8 + chunk) * 256 + d] = ssum;
}

// ---------------------------------------------------------------------------
// Kernel E: context[b][d] = sum_c partials[b][c][d]
// ---------------------------------------------------------------------------
__global__ __launch_bounds__(256) void ke_reduce(
    const float* __restrict__ partials, float* __restrict__ ctx) {
  int b = blockIdx.x;
  int d = threadIdx.x;
  float s = 0.f;
#pragma unroll
  for (int c = 0; c < 8; ++c) s += partials[(size_t)(b * 8 + c) * 256 + d];
  ctx[b * 256 + d] = s;
}

// ---------------------------------------------------------------------------
extern "C" void kernel_launch(void* const* d_in, const int* in_sizes, int n_in,
                              void* d_out, int out_size, void* d_ws,
                              size_t ws_size, hipStream_t stream) {
  const float* features = (const float*)d_in[0];
  const float* hidden = (const float*)d_in[1];
  const float* W1 = (const float*)d_in[2];
  const float* b1 = (const float*)d_in[3];
  const float* W2 = (const float*)d_in[4];
  const float* b2 = (const float*)d_in[5];
  const float* V = (const float*)d_in[6];
  // d_in[7] = bV: softmax is shift-invariant and logits aren't returned -> drop.

  float* ws = (float*)d_ws;
  float* ph = ws;                          // B*U      = 32768 floats
  float* logits = ws + 32768;              // B*L      = 262144 floats
  float* partials = ws + 32768 + 262144;   // B*8*D    = 262144 floats

  float* ctx = (float*)d_out;              // [B, D]  first output
  float* wout = (float*)d_out + B_ * D_;   // [B, L, 1] second output

  ka_proj_h<<<B_, 256, 0, stream>>>(hidden, W2, b1, b2, ph);
  kb_logits<<<B_ * (L_ / TL), 256, 0, stream>>>(features, W1, ph, V, logits);
  kc_softmax<<<B_, 256, 0, stream>>>(logits, wout);
  kd_partial<<<B_ * 8, 256, 0, stream>>>(features, wout, partials);
  ke_reduce<<<B_, 256, 0, stream>>>(partials, ctx);
}

// Round 6
// 505.615 us; speedup vs baseline: 1.4828x; 1.4828x over previous
//
#include <hip/hip_runtime.h>
#include <hip/hip_bf16.h>

#define B_ 128
#define L_ 2048
#define D_ 256
#define H_ 512
#define U_ 256

typedef _Float16 half8 __attribute__((ext_vector_type(8)));
typedef float f32x4 __attribute__((ext_vector_type(4)));

// ---------------------------------------------------------------------------
// Kernel P: W1 [D][U] fp32  ->  W1t_hi/lo [U][D] fp16 (transposed + split)
// x = hi + lo with hi=fp16(x), lo=fp16(x-hi): 22 effective mantissa bits.
// ---------------------------------------------------------------------------
__global__ __launch_bounds__(256) void kp_w1split(
    const float* __restrict__ W1, _Float16* __restrict__ W1t_hi,
    _Float16* __restrict__ W1t_lo) {
  int k = blockIdx.x;   // D_ rows of W1
  int u = threadIdx.x;  // U_ cols
  float x = W1[k * U_ + u];
  _Float16 hi = (_Float16)x;
  _Float16 lo = (_Float16)(x - (float)hi);
  W1t_hi[u * D_ + k] = hi;
  W1t_lo[u * D_ + k] = lo;
}

// ---------------------------------------------------------------------------
// Kernel A: ph[b][u] = b1[u] + b2[u] + sum_k hidden[b][k] * W2[k][u]
// ---------------------------------------------------------------------------
__global__ __launch_bounds__(256) void ka_proj_h(
    const float* __restrict__ hidden, const float* __restrict__ W2,
    const float* __restrict__ b1, const float* __restrict__ b2,
    float* __restrict__ ph) {
  int b = blockIdx.x;
  int u = threadIdx.x;
  __shared__ float hs[H_];
  for (int k = u; k < H_; k += 256) hs[k] = hidden[b * H_ + k];
  __syncthreads();
  float acc = b1[u] + b2[u];
#pragma unroll 8
  for (int k = 0; k < H_; ++k) acc += hs[k] * W2[k * U_ + u];
  ph[b * U_ + u] = acc;
}

// ---------------------------------------------------------------------------
// Kernel B (MFMA): logits[b][l] = sum_u tanh(features·W1 + ph)[l,u] * V[u]
// fp16-split 3-pass GEMM on mfma_f32_16x16x32_f16.
// Block: 256 thr = 4 waves; tile 64 rows x 256 cols; wave w owns cols w*64..+63
// (M-rep 4, N-rep 4 per wave). K chunks of 32.
// LDS rows padded to 40 halves (80 B: 16B-aligned, 2-way bank alias = free).
// ---------------------------------------------------------------------------
#define TLM 64
#define BKC 32

__global__ __launch_bounds__(256, 2) void kb_mfma(
    const float* __restrict__ features, const _Float16* __restrict__ W1t_hi,
    const _Float16* __restrict__ W1t_lo, const float* __restrict__ ph,
    const float* __restrict__ V, float* __restrict__ logits) {
  __shared__ __align__(16) _Float16 Ah[TLM][40], Al[TLM][40];
  __shared__ __align__(16) _Float16 Bh[U_][40], Bl[U_][40];
  __shared__ float red[4][TLM];

  const int tid = threadIdx.x;
  const int w = tid >> 6;
  const int lane = tid & 63;
  const int g = lane >> 4;
  const int c = lane & 15;
  const int bidx = blockIdx.x;
  const int b = bidx >> 5;             // 32 row-tiles per batch
  const int l0 = (bidx & 31) * TLM;
  const int wcol0 = w * 64;
  const float* fbase = features + ((size_t)b * L_ + l0) * D_;

  f32x4 acc[4][4];
#pragma unroll
  for (int mt = 0; mt < 4; ++mt)
#pragma unroll
    for (int nt = 0; nt < 4; ++nt) acc[mt][nt] = (f32x4){0.f, 0.f, 0.f, 0.f};

  for (int kc = 0; kc < D_; kc += BKC) {
    // stage A chunk [64][32] fp32 -> fp16 hi/lo (512 float4, 2/thread)
#pragma unroll
    for (int j = 0; j < 2; ++j) {
      int idx = tid + j * 256;
      int row = idx >> 3;
      int c4 = idx & 7;
      float4 x = *(const float4*)&fbase[(size_t)row * D_ + kc + c4 * 4];
      union { _Float16 h[4]; float2 f; } hh, ll;
      hh.h[0] = (_Float16)x.x; ll.h[0] = (_Float16)(x.x - (float)hh.h[0]);
      hh.h[1] = (_Float16)x.y; ll.h[1] = (_Float16)(x.y - (float)hh.h[1]);
      hh.h[2] = (_Float16)x.z; ll.h[2] = (_Float16)(x.z - (float)hh.h[2]);
      hh.h[3] = (_Float16)x.w; ll.h[3] = (_Float16)(x.w - (float)hh.h[3]);
      *(float2*)&Ah[row][c4 * 4] = hh.f;
      *(float2*)&Al[row][c4 * 4] = ll.f;
    }
    // stage B chunk: Bt[256 u][32 k] from pre-split W1t (1024 float4 per half)
#pragma unroll
    for (int j = 0; j < 4; ++j) {
      int idx = tid + j * 256;
      int row = idx >> 2;
      int q = idx & 3;
      *(float4*)&Bh[row][q * 8] =
          *(const float4*)&W1t_hi[(size_t)row * D_ + kc + q * 8];
      *(float4*)&Bl[row][q * 8] =
          *(const float4*)&W1t_lo[(size_t)row * D_ + kc + q * 8];
    }
    __syncthreads();

    half8 ah[4], al[4];
#pragma unroll
    for (int mt = 0; mt < 4; ++mt) {
      ah[mt] = *(const half8*)&Ah[mt * 16 + c][g * 8];
      al[mt] = *(const half8*)&Al[mt * 16 + c][g * 8];
    }
#pragma unroll
    for (int nt = 0; nt < 4; ++nt) {
      half8 bh = *(const half8*)&Bh[wcol0 + nt * 16 + c][g * 8];
      half8 bl = *(const half8*)&Bl[wcol0 + nt * 16 + c][g * 8];
#pragma unroll
      for (int mt = 0; mt < 4; ++mt) {
        acc[mt][nt] =
            __builtin_amdgcn_mfma_f32_16x16x32_f16(ah[mt], bh, acc[mt][nt], 0, 0, 0);
        acc[mt][nt] =
            __builtin_amdgcn_mfma_f32_16x16x32_f16(ah[mt], bl, acc[mt][nt], 0, 0, 0);
        acc[mt][nt] =
            __builtin_amdgcn_mfma_f32_16x16x32_f16(al[mt], bh, acc[mt][nt], 0, 0, 0);
      }
    }
    __syncthreads();
  }

  // epilogue: tanh + V-dot. C layout: col=lane&15, row=(lane>>4)*4+reg.
  float phv[4], vv[4];
#pragma unroll
  for (int nt = 0; nt < 4; ++nt) {
    int col = wcol0 + nt * 16 + c;
    phv[nt] = ph[b * U_ + col];
    vv[nt] = V[col];
  }
#pragma unroll
  for (int mt = 0; mt < 4; ++mt) {
#pragma unroll
    for (int j = 0; j < 4; ++j) {
      float part = 0.f;
#pragma unroll
      for (int nt = 0; nt < 4; ++nt) {
        float x = acc[mt][nt][j] + phv[nt];
        float e = __expf(2.f * x);
        float t = 1.f - 2.f * __builtin_amdgcn_rcpf(e + 1.f);  // tanh, inf-safe
        part += t * vv[nt];
      }
      part += __shfl_xor(part, 1, 16);
      part += __shfl_xor(part, 2, 16);
      part += __shfl_xor(part, 4, 16);
      part += __shfl_xor(part, 8, 16);
      if (c == 0) red[w][mt * 16 + g * 4 + j] = part;
    }
  }
  __syncthreads();
  if (tid < TLM) {
    logits[b * L_ + l0 + tid] =
        red[0][tid] + red[1][tid] + red[2][tid] + red[3][tid];
  }
}

// ---------------------------------------------------------------------------
// Kernel C: softmax over L per batch; writes attention weights to d_out
// ---------------------------------------------------------------------------
__global__ __launch_bounds__(256) void kc_softmax(
    const float* __restrict__ logits, float* __restrict__ wout) {
  int b = blockIdx.x;
  int tid = threadIdx.x;
  const float* lrow = logits + b * L_;
  float v[8];
  *(float4*)&v[0] = *(const float4*)&lrow[tid * 8];
  *(float4*)&v[4] = *(const float4*)&lrow[tid * 8 + 4];

  float m = v[0];
#pragma unroll
  for (int i = 1; i < 8; ++i) m = fmaxf(m, v[i]);
#pragma unroll
  for (int off = 1; off <= 32; off <<= 1) m = fmaxf(m, __shfl_xor(m, off, 64));
  __shared__ float sm[4];
  if ((tid & 63) == 0) sm[tid >> 6] = m;
  __syncthreads();
  m = fmaxf(fmaxf(sm[0], sm[1]), fmaxf(sm[2], sm[3]));

  float s = 0.f;
#pragma unroll
  for (int i = 0; i < 8; ++i) {
    v[i] = __expf(v[i] - m);
    s += v[i];
  }
#pragma unroll
  for (int off = 1; off <= 32; off <<= 1) s += __shfl_xor(s, off, 64);
  __shared__ float ss[4];
  if ((tid & 63) == 0) ss[tid >> 6] = s;
  __syncthreads();
  s = ss[0] + ss[1] + ss[2] + ss[3];

  float inv = 1.f / s;
#pragma unroll
  for (int i = 0; i < 8; ++i) v[i] *= inv;
  *(float4*)&wout[b * L_ + tid * 8] = *(float4*)&v[0];
  *(float4*)&wout[b * L_ + tid * 8 + 4] = *(float4*)&v[4];
}

// ---------------------------------------------------------------------------
// Kernel D: partials[b][chunk][d] = sum_{l in chunk of 256} w[l]*f[l][d]
// weights staged in LDS once (broadcast reads, conflict-free)
// ---------------------------------------------------------------------------
__global__ __launch_bounds__(256) void kd_partial(
    const float* __restrict__ features, const float* __restrict__ w,
    float* __restrict__ partials) {
  int bidx = blockIdx.x;  // B*8
  int b = bidx >> 3;
  int chunk = bidx & 7;
  int tid = threadIdx.x;
  int lq = tid >> 6;
  int dq = tid & 63;
  __shared__ float wsm[256];
  wsm[tid] = w[b * L_ + chunk * 256 + tid];
  __syncthreads();
  const float* fb =
      features + ((size_t)b * L_ + chunk * 256 + lq * 64) * D_ + dq * 4;
  const float* wl = &wsm[lq * 64];
  float4 acc = {0.f, 0.f, 0.f, 0.f};
#pragma unroll 8
  for (int i = 0; i < 64; ++i) {
    float wt = wl[i];
    float4 fv = *(const float4*)(fb + (size_t)i * D_);
    acc.x += wt * fv.x;
    acc.y += wt * fv.y;
    acc.z += wt * fv.z;
    acc.w += wt * fv.w;
  }
  __shared__ float red[4][256];
  *(float4*)&red[lq][dq * 4] = acc;
  __syncthreads();
  float ssum = red[0][tid] + red[1][tid] + red[2][tid] + red[3][tid];
  partials[(size_t)(b * 8 + chunk) * 256 + tid] = ssum;
}

// ---------------------------------------------------------------------------
// Kernel E: context[b][d] = sum_c partials[b][c][d]
// ---------------------------------------------------------------------------
__global__ __launch_bounds__(256) void ke_reduce(
    const float* __restrict__ partials, float* __restrict__ ctx) {
  int b = blockIdx.x;
  int d = threadIdx.x;
  float s = 0.f;
#pragma unroll
  for (int c = 0; c < 8; ++c) s += partials[(size_t)(b * 8 + c) * 256 + d];
  ctx[b * 256 + d] = s;
}

// ---------------------------------------------------------------------------
extern "C" void kernel_launch(void* const* d_in, const int* in_sizes, int n_in,
                              void* d_out, int out_size, void* d_ws,
                              size_t ws_size, hipStream_t stream) {
  const float* features = (const float*)d_in[0];
  const float* hidden = (const float*)d_in[1];
  const float* W1 = (const float*)d_in[2];
  const float* b1 = (const float*)d_in[3];
  const float* W2 = (const float*)d_in[4];
  const float* b2 = (const float*)d_in[5];
  const float* V = (const float*)d_in[6];
  // d_in[7] = bV: softmax shift-invariant, logits not returned -> dropped.

  float* ws = (float*)d_ws;
  float* ph = ws;                              // 32768 floats
  float* logits = ws + 32768;                  // 262144 floats
  float* partials = ws + 32768 + 262144;       // 262144 floats
  _Float16* W1t_hi = (_Float16*)(ws + 557056); // 65536 halves
  _Float16* W1t_lo = W1t_hi + 65536;           // 65536 halves

  float* ctx = (float*)d_out;             // [B, D]
  float* wout = (float*)d_out + B_ * D_;  // [B, L, 1]

  kp_w1split<<<D_, 256, 0, stream>>>(W1, W1t_hi, W1t_lo);
  ka_proj_h<<<B_, 256, 0, stream>>>(hidden, W2, b1, b2, ph);
  kb_mfma<<<B_ * (L_ / TLM), 256, 0, stream>>>(features, W1t_hi, W1t_lo, ph, V,
                                               logits);
  kc_softmax<<<B_, 256, 0, stream>>>(logits, wout);
  kd_partial<<<B_ * 8, 256, 0, stream>>>(features, wout, partials);
  ke_reduce<<<B_, 256, 0, stream>>>(partials, ctx);
}